// Round 4
// baseline (707.389 us; speedup 1.0000x reference)
//
#include <hip/hip_runtime.h>
#include <hip/hip_bf16.h>
#include <hip/hip_fp16.h>

typedef _Float16 half8  __attribute__((ext_vector_type(8)));
typedef _Float16 half4v __attribute__((ext_vector_type(4)));
typedef float    float4v __attribute__((ext_vector_type(4)));

#define BM 128
#define BN 128
#define BK 32
#define LDW 40   // 32 + 8 halves pad: 80B row stride, keeps 16B alignment

__device__ __forceinline__ float gelu_exact(float v) {
    return 0.5f * v * (1.0f + erff(v * 0.70710678118654752f));
}

// NT GEMM: C(M,N) = epilogue(A(M,K) @ B(N,K)^T + bias)
// AFP16: A source fp16 (else fp32).
// EPI==0: gelu -> fp16 store (intermediate D in ws)
// EPI==1: bias -> fp32 store, fp16-rounded (d_out is float* per harness: output dtype
//         is float16, harness stores non-bf16 outputs as fp32)
template<int AFP16, int EPI>
__global__ __launch_bounds__(256, 2)
void gemm_nt_kernel(const void* __restrict__ Av, const float* __restrict__ B,
                    const float* __restrict__ bias, void* __restrict__ Cout,
                    int M, int N, int K)
{
    __shared__ _Float16 ldsA[BM * LDW];
    __shared__ _Float16 ldsB[BN * LDW];

    const int tid  = threadIdx.x;
    const int lane = tid & 63;
    const int wid  = tid >> 6;     // 4 waves: 2x2 over a 128x128 tile
    const int wm   = wid >> 1;
    const int wn   = wid & 1;
    const int brow = blockIdx.y * BM;
    const int bcol = blockIdx.x * BN;

    const int frow = lane & 15;        // A-row / B-col index of input fragments
    const int fk   = (lane >> 4) * 8;  // k-offset of input fragments
    const int rA   = (lane >> 4) * 4;  // docs-mapping C/D row base

    // ---- Runtime C/D layout probe (one MFMA, exact integer arithmetic) ----
    // A = [I16 | 0] (16x32), B(32x16)[k][c] = k + 100c  ->  D[r][c] = r + 100c.
    // Docs mapping M1: d[g] = (rA+g) + 100*frow; if any lane mismatches, use swap.
    half8 pa, pb;
    #pragma unroll
    for (int e = 0; e < 8; ++e) {
        pa[e] = (_Float16)((frow == fk + e) ? 1.0f : 0.0f);
        pb[e] = (_Float16)(float)((fk + e) + 100 * frow);
    }
    float4v pd = {0.f, 0.f, 0.f, 0.f};
    pd = __builtin_amdgcn_mfma_f32_16x16x32_f16(pa, pb, pd, 0, 0, 0);
    const bool m1_ok = (pd[0] == (float)(rA + 0 + 100 * frow)) &&
                       (pd[1] == (float)(rA + 1 + 100 * frow));
    const bool swap_cd = (__ballot(m1_ok) != ~0ull);

    float4v acc[4][4];
    #pragma unroll
    for (int m = 0; m < 4; ++m)
        #pragma unroll
        for (int n = 0; n < 4; ++n)
            acc[m][n] = (float4v){0.f, 0.f, 0.f, 0.f};

    const int NK = K / BK;
    for (int kt = 0; kt < NK; ++kt) {
        const int k0 = kt * BK;
        // Stage 128x32 A-tile and B-tile (convert to fp16 as needed).
        #pragma unroll
        for (int i = 0; i < 4; ++i) {
            const int idx = i * 256 + tid;   // 0..1023
            const int r = idx >> 3;          // 0..127
            const int c = (idx & 7) * 4;     // 0..28
            half4v h;
            if constexpr (AFP16) {
                h = *reinterpret_cast<const half4v*>(
                        reinterpret_cast<const _Float16*>(Av) + (size_t)(brow + r) * K + k0 + c);
            } else {
                const float4v v = *reinterpret_cast<const float4v*>(
                        reinterpret_cast<const float*>(Av) + (size_t)(brow + r) * K + k0 + c);
                h[0] = (_Float16)v[0]; h[1] = (_Float16)v[1];
                h[2] = (_Float16)v[2]; h[3] = (_Float16)v[3];
            }
            *reinterpret_cast<half4v*>(&ldsA[r * LDW + c]) = h;

            const float4v w = *reinterpret_cast<const float4v*>(
                    B + (size_t)(bcol + r) * K + k0 + c);
            half4v hw;
            hw[0] = (_Float16)w[0]; hw[1] = (_Float16)w[1];
            hw[2] = (_Float16)w[2]; hw[3] = (_Float16)w[3];
            *reinterpret_cast<half4v*>(&ldsB[r * LDW + c]) = hw;
        }
        __syncthreads();

        half8 af[4], bf[4];
        #pragma unroll
        for (int m = 0; m < 4; ++m)
            af[m] = *reinterpret_cast<const half8*>(
                        &ldsA[(wm * 64 + m * 16 + frow) * LDW + fk]);
        #pragma unroll
        for (int n = 0; n < 4; ++n)
            bf[n] = *reinterpret_cast<const half8*>(
                        &ldsB[(wn * 64 + n * 16 + frow) * LDW + fk]);

        #pragma unroll
        for (int m = 0; m < 4; ++m)
            #pragma unroll
            for (int n = 0; n < 4; ++n)
                acc[m][n] = __builtin_amdgcn_mfma_f32_16x16x32_f16(af[m], bf[n], acc[m][n], 0, 0, 0);

        __syncthreads();
    }

    // Epilogue: mapping chosen by the probe.
    #pragma unroll
    for (int m = 0; m < 4; ++m) {
        #pragma unroll
        for (int n = 0; n < 4; ++n) {
            #pragma unroll
            for (int g = 0; g < 4; ++g) {
                const int fr = swap_cd ? frow      : (rA + g);
                const int fc = swap_cd ? (rA + g)  : frow;
                const int gr = brow + wm * 64 + m * 16 + fr;
                const int gc = bcol + wn * 64 + n * 16 + fc;
                const float v = acc[m][n][g] + bias[gc];
                if constexpr (EPI == 0) {
                    reinterpret_cast<_Float16*>(Cout)[(size_t)gr * N + gc] =
                        (_Float16)gelu_exact(v);
                } else {
                    // d_out is float* (reference output fp16 -> harness stores fp32).
                    // Round through fp16 to match reference rounding exactly.
                    reinterpret_cast<float*>(Cout)[(size_t)gr * N + gc] =
                        (float)(_Float16)v;
                }
            }
        }
    }
}

extern "C" void kernel_launch(void* const* d_in, const int* in_sizes, int n_in,
                              void* d_out, int out_size, void* d_ws, size_t ws_size,
                              hipStream_t stream) {
    const float* x  = (const float*)d_in[0];
    const float* W0 = (const float*)d_in[1];
    const float* b0 = (const float*)d_in[2];
    const float* W1 = (const float*)d_in[3];
    const float* b1 = (const float*)d_in[4];

    const int N = in_sizes[2];           // 8192
    const int H = in_sizes[4];           // 2048
    const int M = in_sizes[0] / H;       // 4096

    _Float16* D = (_Float16*)d_ws;       // M*N fp16 = 64 MB intermediate
    float* out = (float*)d_out;

    // GEMM0: D = gelu(X @ W0^T + b0)
    gemm_nt_kernel<0, 0><<<dim3(N / BN, M / BM), dim3(256), 0, stream>>>(
        x, W0, b0, D, M, N, H);
    // GEMM1: out = D @ W1^T + b1
    gemm_nt_kernel<1, 1><<<dim3(H / BN, M / BM), dim3(256), 0, stream>>>(
        D, W1, b1, (void*)out, M, H, N);
}

// Round 5
// 554.666 us; speedup vs baseline: 1.2753x; 1.2753x over previous
//
#include <hip/hip_runtime.h>
#include <hip/hip_bf16.h>
#include <hip/hip_fp16.h>

typedef _Float16 half8  __attribute__((ext_vector_type(8)));
typedef _Float16 half4v __attribute__((ext_vector_type(4)));
typedef float    float4v __attribute__((ext_vector_type(4)));

#define BM 128
#define BN 128
#define BK 32
#define LDW 40   // fallback-path pad

__device__ __forceinline__ float gelu_exact(float v) {
    return 0.5f * v * (1.0f + erff(v * 0.70710678118654752f));
}

// ---------------------------------------------------------------------------
// fp32 -> fp16 cast, vectorized (float4 in, half4 out), grid-stride
// ---------------------------------------------------------------------------
__global__ __launch_bounds__(256)
void cast_f32_f16_kernel(const float* __restrict__ in, _Float16* __restrict__ out, int n4) {
    int i = blockIdx.x * blockDim.x + threadIdx.x;
    const int stride = gridDim.x * blockDim.x;
    for (; i < n4; i += stride) {
        const float4v v = reinterpret_cast<const float4v*>(in)[i];
        half4v h;
        h[0] = (_Float16)v[0]; h[1] = (_Float16)v[1];
        h[2] = (_Float16)v[2]; h[3] = (_Float16)v[3];
        reinterpret_cast<half4v*>(out)[i] = h;
    }
}

// ---------------------------------------------------------------------------
// Fast path: fp16 NT GEMM, m97 structure (global_load_lds width16, dbuf LDS,
// prefetch + single barrier per K-step). C = epi(A(M,K) @ B(N,K)^T + bias).
// EPI==0: gelu -> fp16 store. EPI==1: fp16-rounded fp32 store.
// ---------------------------------------------------------------------------
template<int EPI>
__global__ __launch_bounds__(256, 2)
void gemm_nt_f16_kernel(const _Float16* __restrict__ A, const _Float16* __restrict__ B,
                        const float* __restrict__ bias, void* __restrict__ Cout,
                        int M, int N, int K)
{
    // linear [128][32] tiles (global_load_lds requires linear lane-order dest)
    __shared__ _Float16 ldsA[2][BM * BK];
    __shared__ _Float16 ldsB[2][BN * BK];

    const int tid  = threadIdx.x;
    const int lane = tid & 63;
    const int wid  = tid >> 6;     // 4 waves: 2x2 over the 128x128 tile
    const int wm   = wid >> 1;
    const int wn   = wid & 1;
    const int brow = blockIdx.y * BM;
    const int bcol = blockIdx.x * BN;

    const int frow = lane & 15;        // A-row / B-col of input fragments
    const int fk   = (lane >> 4) * 8;  // k-offset of input fragments
    const int rA   = (lane >> 4) * 4;  // docs-mapping C/D row base

    // ---- Runtime C/D layout probe (same as proven round-4 kernel) ----
    half8 pa, pb;
    #pragma unroll
    for (int e = 0; e < 8; ++e) {
        pa[e] = (_Float16)((frow == fk + e) ? 1.0f : 0.0f);
        pb[e] = (_Float16)(float)((fk + e) + 100 * frow);
    }
    float4v pd = {0.f, 0.f, 0.f, 0.f};
    pd = __builtin_amdgcn_mfma_f32_16x16x32_f16(pa, pb, pd, 0, 0, 0);
    const bool m1_ok = (pd[0] == (float)(rA + 0 + 100 * frow)) &&
                       (pd[1] == (float)(rA + 1 + 100 * frow));
    const bool swap_cd = (__ballot(m1_ok) != ~0ull);

    // Per-lane staging source offsets: chunk = wid*2 + c covers rows
    // [chunk*16, chunk*16+16); lane covers row chunk*16 + lane/4, col (lane&3)*8.
    const int sr = (lane >> 2);        // 0..15 row within chunk
    const int sc = (lane & 3) * 8;     // 0..24 col (halves)

    auto stage = [&](int kt, int buf) {
        const int k0 = kt * BK;
        #pragma unroll
        for (int c = 0; c < 2; ++c) {
            const int chunk = wid * 2 + c;
            const int row = chunk * 16 + sr;
            const _Float16* gA = A + (size_t)(brow + row) * K + k0 + sc;
            __builtin_amdgcn_global_load_lds(
                (const __attribute__((address_space(1))) void*)gA,
                (__attribute__((address_space(3))) void*)&ldsA[buf][chunk * 512],
                16, 0, 0);
            const _Float16* gB = B + (size_t)(bcol + row) * K + k0 + sc;
            __builtin_amdgcn_global_load_lds(
                (const __attribute__((address_space(1))) void*)gB,
                (__attribute__((address_space(3))) void*)&ldsB[buf][chunk * 512],
                16, 0, 0);
        }
    };

    float4v acc[4][4];
    #pragma unroll
    for (int m = 0; m < 4; ++m)
        #pragma unroll
        for (int n = 0; n < 4; ++n)
            acc[m][n] = (float4v){0.f, 0.f, 0.f, 0.f};

    const int NK = K / BK;
    stage(0, 0);
    __syncthreads();           // drains vmcnt(0) then barrier

    int cur = 0;
    for (int kt = 0; kt < NK; ++kt) {
        if (kt + 1 < NK) stage(kt + 1, cur ^ 1);   // prefetch into other buffer

        half8 af[4], bf[4];
        #pragma unroll
        for (int m = 0; m < 4; ++m)
            af[m] = *reinterpret_cast<const half8*>(
                        &ldsA[cur][(wm * 64 + m * 16 + frow) * BK + fk]);
        #pragma unroll
        for (int n = 0; n < 4; ++n)
            bf[n] = *reinterpret_cast<const half8*>(
                        &ldsB[cur][(wn * 64 + n * 16 + frow) * BK + fk]);

        #pragma unroll
        for (int m = 0; m < 4; ++m)
            #pragma unroll
            for (int n = 0; n < 4; ++n)
                acc[m][n] = __builtin_amdgcn_mfma_f32_16x16x32_f16(af[m], bf[n], acc[m][n], 0, 0, 0);

        __syncthreads();       // vmcnt(0)+lgkmcnt(0)+barrier: prefetch landed, reads done
        cur ^= 1;
    }

    #pragma unroll
    for (int m = 0; m < 4; ++m) {
        #pragma unroll
        for (int n = 0; n < 4; ++n) {
            #pragma unroll
            for (int g = 0; g < 4; ++g) {
                const int fr = swap_cd ? frow     : (rA + g);
                const int fc = swap_cd ? (rA + g) : frow;
                const int gr = brow + wm * 64 + m * 16 + fr;
                const int gc = bcol + wn * 64 + n * 16 + fc;
                const float v = acc[m][n][g] + bias[gc];
                if constexpr (EPI == 0) {
                    reinterpret_cast<_Float16*>(Cout)[(size_t)gr * N + gc] =
                        (_Float16)gelu_exact(v);
                } else {
                    reinterpret_cast<float*>(Cout)[(size_t)gr * N + gc] =
                        (float)(_Float16)v;
                }
            }
        }
    }
}

// ---------------------------------------------------------------------------
// Fallback path: proven round-4 kernel (fused fp32 staging, single buffer)
// ---------------------------------------------------------------------------
template<int AFP16, int EPI>
__global__ __launch_bounds__(256, 2)
void gemm_nt_kernel(const void* __restrict__ Av, const float* __restrict__ B,
                    const float* __restrict__ bias, void* __restrict__ Cout,
                    int M, int N, int K)
{
    __shared__ _Float16 ldsA[BM * LDW];
    __shared__ _Float16 ldsB[BN * LDW];

    const int tid  = threadIdx.x;
    const int lane = tid & 63;
    const int wid  = tid >> 6;
    const int wm   = wid >> 1;
    const int wn   = wid & 1;
    const int brow = blockIdx.y * BM;
    const int bcol = blockIdx.x * BN;

    const int frow = lane & 15;
    const int fk   = (lane >> 4) * 8;
    const int rA   = (lane >> 4) * 4;

    half8 pa, pb;
    #pragma unroll
    for (int e = 0; e < 8; ++e) {
        pa[e] = (_Float16)((frow == fk + e) ? 1.0f : 0.0f);
        pb[e] = (_Float16)(float)((fk + e) + 100 * frow);
    }
    float4v pd = {0.f, 0.f, 0.f, 0.f};
    pd = __builtin_amdgcn_mfma_f32_16x16x32_f16(pa, pb, pd, 0, 0, 0);
    const bool m1_ok = (pd[0] == (float)(rA + 0 + 100 * frow)) &&
                       (pd[1] == (float)(rA + 1 + 100 * frow));
    const bool swap_cd = (__ballot(m1_ok) != ~0ull);

    float4v acc[4][4];
    #pragma unroll
    for (int m = 0; m < 4; ++m)
        #pragma unroll
        for (int n = 0; n < 4; ++n)
            acc[m][n] = (float4v){0.f, 0.f, 0.f, 0.f};

    const int NK = K / BK;
    for (int kt = 0; kt < NK; ++kt) {
        const int k0 = kt * BK;
        #pragma unroll
        for (int i = 0; i < 4; ++i) {
            const int idx = i * 256 + tid;
            const int r = idx >> 3;
            const int c = (idx & 7) * 4;
            half4v h;
            if constexpr (AFP16) {
                h = *reinterpret_cast<const half4v*>(
                        reinterpret_cast<const _Float16*>(Av) + (size_t)(brow + r) * K + k0 + c);
            } else {
                const float4v v = *reinterpret_cast<const float4v*>(
                        reinterpret_cast<const float*>(Av) + (size_t)(brow + r) * K + k0 + c);
                h[0] = (_Float16)v[0]; h[1] = (_Float16)v[1];
                h[2] = (_Float16)v[2]; h[3] = (_Float16)v[3];
            }
            *reinterpret_cast<half4v*>(&ldsA[r * LDW + c]) = h;

            const float4v w = *reinterpret_cast<const float4v*>(
                    B + (size_t)(bcol + r) * K + k0 + c);
            half4v hw;
            hw[0] = (_Float16)w[0]; hw[1] = (_Float16)w[1];
            hw[2] = (_Float16)w[2]; hw[3] = (_Float16)w[3];
            *reinterpret_cast<half4v*>(&ldsB[r * LDW + c]) = hw;
        }
        __syncthreads();

        half8 af[4], bf[4];
        #pragma unroll
        for (int m = 0; m < 4; ++m)
            af[m] = *reinterpret_cast<const half8*>(
                        &ldsA[(wm * 64 + m * 16 + frow) * LDW + fk]);
        #pragma unroll
        for (int n = 0; n < 4; ++n)
            bf[n] = *reinterpret_cast<const half8*>(
                        &ldsB[(wn * 64 + n * 16 + frow) * LDW + fk]);

        #pragma unroll
        for (int m = 0; m < 4; ++m)
            #pragma unroll
            for (int n = 0; n < 4; ++n)
                acc[m][n] = __builtin_amdgcn_mfma_f32_16x16x32_f16(af[m], bf[n], acc[m][n], 0, 0, 0);

        __syncthreads();
    }

    #pragma unroll
    for (int m = 0; m < 4; ++m) {
        #pragma unroll
        for (int n = 0; n < 4; ++n) {
            #pragma unroll
            for (int g = 0; g < 4; ++g) {
                const int fr = swap_cd ? frow     : (rA + g);
                const int fc = swap_cd ? (rA + g) : frow;
                const int gr = brow + wm * 64 + m * 16 + fr;
                const int gc = bcol + wn * 64 + n * 16 + fc;
                const float v = acc[m][n][g] + bias[gc];
                if constexpr (EPI == 0) {
                    reinterpret_cast<_Float16*>(Cout)[(size_t)gr * N + gc] =
                        (_Float16)gelu_exact(v);
                } else {
                    reinterpret_cast<float*>(Cout)[(size_t)gr * N + gc] =
                        (float)(_Float16)v;
                }
            }
        }
    }
}

extern "C" void kernel_launch(void* const* d_in, const int* in_sizes, int n_in,
                              void* d_out, int out_size, void* d_ws, size_t ws_size,
                              hipStream_t stream) {
    const float* x  = (const float*)d_in[0];
    const float* W0 = (const float*)d_in[1];
    const float* b0 = (const float*)d_in[2];
    const float* W1 = (const float*)d_in[3];
    const float* b1 = (const float*)d_in[4];

    const int N = in_sizes[2];           // 8192
    const int H = in_sizes[4];           // 2048
    const int M = in_sizes[0] / H;       // 4096

    const size_t szX  = (size_t)M * H;   // 8M halves
    const size_t szW0 = (size_t)N * H;   // 16M
    const size_t szW1 = (size_t)H * N;   // 16M
    const size_t szD  = (size_t)M * N;   // 32M

    const size_t need = (szX + szW0 + szW1 + szD) * sizeof(_Float16);  // 144 MB

    if (ws_size >= need) {
        _Float16* Xh  = (_Float16*)d_ws;
        _Float16* W0h = Xh + szX;
        _Float16* W1h = W0h + szW0;
        _Float16* D   = W1h + szW1;

        cast_f32_f16_kernel<<<2048, 256, 0, stream>>>(x,  Xh,  (int)(szX  / 4));
        cast_f32_f16_kernel<<<2048, 256, 0, stream>>>(W0, W0h, (int)(szW0 / 4));
        cast_f32_f16_kernel<<<2048, 256, 0, stream>>>(W1, W1h, (int)(szW1 / 4));

        gemm_nt_f16_kernel<0><<<dim3(N / BN, M / BM), dim3(256), 0, stream>>>(
            Xh, W0h, b0, D, M, N, H);
        gemm_nt_f16_kernel<1><<<dim3(H / BN, M / BM), dim3(256), 0, stream>>>(
            D, W1h, b1, d_out, M, H, N);
    } else {
        _Float16* D = (_Float16*)d_ws;
        gemm_nt_kernel<0, 0><<<dim3(N / BN, M / BM), dim3(256), 0, stream>>>(
            x, W0, b0, D, M, N, H);
        gemm_nt_kernel<1, 1><<<dim3(H / BN, M / BM), dim3(256), 0, stream>>>(
            D, W1, b1, d_out, M, H, N);
    }
}

// Round 6
// 517.575 us; speedup vs baseline: 1.3667x; 1.0717x over previous
//
#include <hip/hip_runtime.h>
#include <hip/hip_fp16.h>

typedef _Float16 half8  __attribute__((ext_vector_type(8)));
typedef _Float16 half4v __attribute__((ext_vector_type(4)));
typedef float    float4v __attribute__((ext_vector_type(4)));

#define BM 256
#define BN 128
#define BK 64
#define THREADS 512
#define BUFH 24576                 // halves per buffer: A(256x64)=16384 + B(128x64)=8192
#define LDS_BYTES (3 * BUFH * 2)   // 147456 B (3 buffers, needs dynamic LDS opt-in)

#define BAR() __builtin_amdgcn_s_barrier()
#define LGKM0() do { asm volatile("s_waitcnt lgkmcnt(0)" ::: "memory"); \
                     __builtin_amdgcn_sched_barrier(0); } while (0)
#define VMC(n) do { asm volatile("s_waitcnt vmcnt(" #n ")" ::: "memory"); \
                    __builtin_amdgcn_sched_barrier(0); } while (0)

__device__ __forceinline__ float gelu_exact(float v) {
    return 0.5f * v * (1.0f + erff(v * 0.70710678118654752f));
}

// Stage one 128x64 fp16 half-tile (g = row0 of half, k-offset pre-added) into LDS.
// Linear LDS dest (global_load_lds requirement); source address pre-swizzled with
// col ^= (row&7)<<4 (bytes) so that swizzled ds_reads see the logical layout (rule 21).
__device__ __forceinline__ void stage_half(const _Float16* __restrict__ g, int lda,
                                           _Float16* ldsdst, int tid) {
    const int r  = tid >> 3;                           // 0..63 (row within 64-row chunk)
    const int ch = ((tid & 7) << 3) ^ ((r & 7) << 3);  // col in halves, pre-swizzled
    const int wslot = (tid >> 6) << 9;                 // wid*512 halves, wave-uniform
    #pragma unroll
    for (int c = 0; c < 2; ++c) {
        __builtin_amdgcn_global_load_lds(
            (const __attribute__((address_space(1))) void*)(g + (size_t)(c * 64 + r) * lda + ch),
            (__attribute__((address_space(3))) void*)(ldsdst + c * 4096 + wslot),
            16, 0, 0);
    }
}

// ---------------------------------------------------------------------------
// fp32 -> fp16 cast, vectorized, grid-stride
// ---------------------------------------------------------------------------
__global__ __launch_bounds__(256)
void cast_f32_f16_kernel(const float* __restrict__ in, _Float16* __restrict__ out, int n4) {
    int i = blockIdx.x * blockDim.x + threadIdx.x;
    const int stride = gridDim.x * blockDim.x;
    for (; i < n4; i += stride) {
        const float4v v = reinterpret_cast<const float4v*>(in)[i];
        half4v h;
        h[0] = (_Float16)v[0]; h[1] = (_Float16)v[1];
        h[2] = (_Float16)v[2]; h[3] = (_Float16)v[3];
        reinterpret_cast<half4v*>(out)[i] = h;
    }
}

// ---------------------------------------------------------------------------
// Pipelined NT GEMM: C(M,Nd) = epi(A(M,K) @ B(Nd,K)^T + bias)
// 256x128 tile, BK=64, 8 waves (2Mx4N, per-wave 128x32), 2 phases/K-tile
// (16 MFMA each), 3 LDS buffers, counted vmcnt(4), T2 swizzle, T5 setprio.
// EPI==0: gelu -> fp16. EPI==1: fp16-rounded fp32 store (harness out buffer).
// ---------------------------------------------------------------------------
template<int EPI>
__global__ __launch_bounds__(THREADS, 2)
void gemm8p(const _Float16* __restrict__ A, const _Float16* __restrict__ B,
            const float* __restrict__ bias, void* __restrict__ Cout,
            int M, int Nd, int K, int Mtiles, int Ntiles)
{
    extern __shared__ __align__(16) char smem[];
    _Float16* lds = (_Float16*)smem;

    const int tid  = threadIdx.x;
    const int lane = tid & 63;
    const int wid  = tid >> 6;
    const int wm   = wid >> 2;      // 0..1
    const int wn   = wid & 3;       // 0..3

    // XCD-aware swizzle (nwg % 8 == 0 for both launches), m-fastest tile decode.
    const int nwg = Mtiles * Ntiles;
    const int bid = blockIdx.x;
    const int swz = (bid & 7) * (nwg >> 3) + (bid >> 3);
    const int tm = swz % Mtiles;
    const int tn = swz / Mtiles;
    const int brow = tm * BM;
    const int bcol = tn * BN;

    const int frow = lane & 15;
    const int fk   = (lane >> 4) * 8;
    const int rA   = (lane >> 4) * 4;

    // ---- runtime C/D layout probe (validated rounds 4-5) ----
    half8 pa, pb;
    #pragma unroll
    for (int e = 0; e < 8; ++e) {
        pa[e] = (_Float16)((frow == fk + e) ? 1.0f : 0.0f);
        pb[e] = (_Float16)(float)((fk + e) + 100 * frow);
    }
    float4v pd = {0.f, 0.f, 0.f, 0.f};
    pd = __builtin_amdgcn_mfma_f32_16x16x32_f16(pa, pb, pd, 0, 0, 0);
    const bool m1_ok = (pd[0] == (float)(rA + 0 + 100 * frow)) &&
                       (pd[1] == (float)(rA + 1 + 100 * frow));
    const bool swap_cd = (__ballot(m1_ok) != ~0ull);

    // per-lane swizzled LDS read offsets (bytes)
    const int lrow = frow << 7;               // row * 128B
    const int xr   = (lane & 7) << 4;
    const int g16  = ((lane >> 4) & 3) << 4;
    const int c0   = g16 ^ xr;                // ks=0 col
    const int c1   = (64 + g16) ^ xr;         // ks=1 col

    const _Float16* Ag0 = A + (size_t)brow * K;
    const _Float16* Ag1 = A + (size_t)(brow + 128) * K;
    const _Float16* Bg  = B + (size_t)bcol * K;

    const int NT = K >> 6;

    // ---- prologue: stage tiles 0,1 (order: B,A0,A1 per tile) ----
    stage_half(Bg,       K, lds + 0 * BUFH + 16384, tid);
    stage_half(Ag0,      K, lds + 0 * BUFH,         tid);
    stage_half(Ag1,      K, lds + 0 * BUFH + 8192,  tid);
    stage_half(Bg  + 64, K, lds + 1 * BUFH + 16384, tid);
    stage_half(Ag0 + 64, K, lds + 1 * BUFH,         tid);
    stage_half(Ag1 + 64, K, lds + 1 * BUFH + 8192,  tid);
    VMC(6);                 // tile 0 fully landed; tile 1 may be in flight
    BAR();

    float4v acc[8][2];
    #pragma unroll
    for (int m = 0; m < 8; ++m) {
        acc[m][0] = (float4v){0.f, 0.f, 0.f, 0.f};
        acc[m][1] = (float4v){0.f, 0.f, 0.f, 0.f};
    }

    half8 afr[4][2], bfr[2][2];

    int b0 = 0, b1 = 1, b2 = 2;
    for (int t = 0; t < NT; ++t) {
        const char* Lc   = (const char*)(lds + b0 * BUFH);
        _Float16*   Ln   = lds + b2 * BUFH;
        const char* Ablk = Lc + wm * 16384;
        const char* Bblk = Lc + 32768 + (wn << 12);
        const bool pre = (t + 2 < NT);

        // ======== phase A: read A-low + B, MFMA fm 0..3 ========
        #pragma unroll
        for (int fm = 0; fm < 4; ++fm) {
            afr[fm][0] = *(const half8*)(Ablk + (fm << 11) + lrow + c0);
            afr[fm][1] = *(const half8*)(Ablk + (fm << 11) + lrow + c1);
        }
        #pragma unroll
        for (int fn = 0; fn < 2; ++fn) {
            bfr[fn][0] = *(const half8*)(Bblk + (fn << 11) + lrow + c0);
            bfr[fn][1] = *(const half8*)(Bblk + (fn << 11) + lrow + c1);
        }
        if (pre) {  // stage tile t+2: B (free since prev phase A), A0 (free since prev phase B)
            stage_half(Bg  + (size_t)(t + 2) * 64, K, Ln + 16384, tid);
            stage_half(Ag0 + (size_t)(t + 2) * 64, K, Ln,         tid);
        }
        BAR();
        LGKM0();
        __builtin_amdgcn_s_setprio(1);
        #pragma unroll
        for (int ks = 0; ks < 2; ++ks)
            #pragma unroll
            for (int fm = 0; fm < 4; ++fm)
                #pragma unroll
                for (int fn = 0; fn < 2; ++fn)
                    acc[fm][fn] = __builtin_amdgcn_mfma_f32_16x16x32_f16(
                        afr[fm][ks], bfr[fn][ks], acc[fm][fn], 0, 0, 0);
        __builtin_amdgcn_s_setprio(0);
        BAR();

        // ======== phase B: read A-high, MFMA fm 4..7 ========
        #pragma unroll
        for (int fm = 0; fm < 4; ++fm) {
            afr[fm][0] = *(const half8*)(Ablk + ((4 + fm) << 11) + lrow + c0);
            afr[fm][1] = *(const half8*)(Ablk + ((4 + fm) << 11) + lrow + c1);
        }
        if (pre) stage_half(Ag1 + (size_t)(t + 2) * 64, K, Ln + 8192, tid);
        if (pre) { VMC(4); } else { VMC(0); }   // counted: last 2 halves stay in flight
        BAR();
        LGKM0();
        __builtin_amdgcn_s_setprio(1);
        #pragma unroll
        for (int ks = 0; ks < 2; ++ks)
            #pragma unroll
            for (int fm = 0; fm < 4; ++fm)
                #pragma unroll
                for (int fn = 0; fn < 2; ++fn)
                    acc[4 + fm][fn] = __builtin_amdgcn_mfma_f32_16x16x32_f16(
                        afr[fm][ks], bfr[fn][ks], acc[4 + fm][fn], 0, 0, 0);
        __builtin_amdgcn_s_setprio(0);
        BAR();

        const int tb = b0; b0 = b1; b1 = b2; b2 = tb;
    }

    // ---- epilogue ----
    #pragma unroll
    for (int fm = 0; fm < 8; ++fm) {
        #pragma unroll
        for (int fn = 0; fn < 2; ++fn) {
            #pragma unroll
            for (int g = 0; g < 4; ++g) {
                const int fr = swap_cd ? frow : (rA + g);
                const int fc = swap_cd ? (rA + g) : frow;
                const int gr = brow + wm * 128 + fm * 16 + fr;
                const int gc = bcol + wn * 32 + fn * 16 + fc;
                const float v = acc[fm][fn][g] + bias[gc];
                if constexpr (EPI == 0) {
                    ((_Float16*)Cout)[(size_t)gr * Nd + gc] = (_Float16)gelu_exact(v);
                } else {
                    ((float*)Cout)[(size_t)gr * Nd + gc] = (float)(_Float16)v;
                }
            }
        }
    }
}

extern "C" void kernel_launch(void* const* d_in, const int* in_sizes, int n_in,
                              void* d_out, int out_size, void* d_ws, size_t ws_size,
                              hipStream_t stream) {
    const float* x  = (const float*)d_in[0];
    const float* W0 = (const float*)d_in[1];
    const float* b0 = (const float*)d_in[2];
    const float* W1 = (const float*)d_in[3];
    const float* b1 = (const float*)d_in[4];

    const int N = in_sizes[2];           // 8192
    const int H = in_sizes[4];           // 2048
    const int M = in_sizes[0] / H;       // 4096

    const size_t szX  = (size_t)M * H;
    const size_t szW0 = (size_t)N * H;
    const size_t szW1 = (size_t)H * N;

    _Float16* Xh  = (_Float16*)d_ws;
    _Float16* W0h = Xh + szX;
    _Float16* W1h = W0h + szW0;
    _Float16* D   = W1h + szW1;          // M*N fp16 intermediate

    cast_f32_f16_kernel<<<2048, 256, 0, stream>>>(x,  Xh,  (int)(szX  / 4));
    cast_f32_f16_kernel<<<2048, 256, 0, stream>>>(W0, W0h, (int)(szW0 / 4));
    cast_f32_f16_kernel<<<2048, 256, 0, stream>>>(W1, W1h, (int)(szW1 / 4));

    (void)hipFuncSetAttribute(reinterpret_cast<const void*>(gemm8p<0>),
                              hipFuncAttributeMaxDynamicSharedMemorySize, LDS_BYTES);
    (void)hipFuncSetAttribute(reinterpret_cast<const void*>(gemm8p<1>),
                              hipFuncAttributeMaxDynamicSharedMemorySize, LDS_BYTES);

    // GEMM0: D = gelu(Xh @ W0h^T + b0)   M=4096, Nd=8192, K=2048  -> 16x64 = 1024 wgs
    gemm8p<0><<<dim3((M / BM) * (N / BN)), dim3(THREADS), LDS_BYTES, stream>>>(
        Xh, W0h, b0, D, M, N, H, M / BM, N / BN);
    // GEMM1: out = D @ W1h^T + b1        M=4096, Nd=2048, K=8192  -> 16x16 = 256 wgs
    gemm8p<1><<<dim3((M / BM) * (H / BN)), dim3(THREADS), LDS_BYTES, stream>>>(
        D, W1h, b1, d_out, M, H, N, M / BM, H / BN);
}

// Round 7
// 482.867 us; speedup vs baseline: 1.4650x; 1.0719x over previous
//
#include <hip/hip_runtime.h>
#include <hip/hip_fp16.h>

typedef _Float16 half8  __attribute__((ext_vector_type(8)));
typedef _Float16 half4v __attribute__((ext_vector_type(4)));
typedef float    float4v __attribute__((ext_vector_type(4)));

#define BAR() __builtin_amdgcn_s_barrier()
#define LGKM(n) do { asm volatile("s_waitcnt lgkmcnt(" #n ")" ::: "memory"); \
                     __builtin_amdgcn_sched_barrier(0); } while (0)
#define VMC(n) do { asm volatile("s_waitcnt vmcnt(" #n ")" ::: "memory"); \
                    __builtin_amdgcn_sched_barrier(0); } while (0)

__device__ __forceinline__ float gelu_exact(float v) {
    return 0.5f * v * (1.0f + erff(v * 0.70710678118654752f));
}

// Stage one 128x64-half fp16 half-tile into LDS (linear dest, source col
// pre-swizzled with byte^=(row&7)<<4 so swizzled ds_reads see logical layout).
template<int T>
__device__ __forceinline__ void stage_half(const _Float16* __restrict__ g, int ldk,
                                           _Float16* dstbase, int tid) {
    constexpr int RP = T / 8;          // rows per pass
    #pragma unroll
    for (int p = 0; p < 128 / RP; ++p) {
        const int r  = p * RP + (tid >> 3);
        const int ch = ((tid & 7) << 3) ^ ((r & 7) << 3);   // halves
        __builtin_amdgcn_global_load_lds(
            (const __attribute__((address_space(1))) void*)(g + (size_t)r * ldk + ch),
            (__attribute__((address_space(3))) void*)(dstbase + p * RP * 64 + (tid >> 6) * 512),
            16, 0, 0);
    }
}

__global__ __launch_bounds__(256)
void cast_f32_f16_kernel(const float* __restrict__ in, _Float16* __restrict__ out, int n4) {
    int i = blockIdx.x * blockDim.x + threadIdx.x;
    const int stride = gridDim.x * blockDim.x;
    for (; i < n4; i += stride) {
        const float4v v = reinterpret_cast<const float4v*>(in)[i];
        half4v h;
        h[0] = (_Float16)v[0]; h[1] = (_Float16)v[1];
        h[2] = (_Float16)v[2]; h[3] = (_Float16)v[3];
        reinterpret_cast<half4v*>(out)[i] = h;
    }
}

// ---------------------------------------------------------------------------
// NT GEMM, per-wave 128x64 output. BM=256, BN=WN*64, BK=64.
// WN=4: 8 waves (2Mx4N), 512 thr, LDS 128KB. WN=2: 4 waves (2Mx2N), 256 thr, 96KB.
// Per K-tile: [phaseA reads A(16)+Bfn01(4)] [stage t+1] [phaseB reads Bfn23(4)]
// lgkm(4) -> 32 MFMA -> lgkm(0) -> 32 MFMA -> vmcnt(0)+barrier. One barrier/tile.
// ---------------------------------------------------------------------------
template<int WN, int THREADS, int EPI>
__global__ __launch_bounds__(THREADS, THREADS / 256)
void gemm_pw(const _Float16* __restrict__ A, const _Float16* __restrict__ B,
             const float* __restrict__ bias, void* __restrict__ Cout,
             int M, int Nd, int K, int Mtiles, int Ntiles)
{
    constexpr int BUFH = 16384 + WN * 4096;   // halves per buffer (A 256x64 + B BNx64)
    extern __shared__ __align__(16) char smem[];
    _Float16* lds = (_Float16*)smem;

    const int tid  = threadIdx.x;
    const int lane = tid & 63;
    const int wid  = tid >> 6;
    const int wm   = (WN == 4) ? (wid >> 2) : (wid >> 1);
    const int wn   = wid & (WN - 1);

    // XCD-aware swizzle (nwg % 8 == 0 for both launches), m-fastest decode.
    const int nwg = Mtiles * Ntiles;
    const int bid = blockIdx.x;
    const int swz = (bid & 7) * (nwg >> 3) + (bid >> 3);
    const int brow = (swz % Mtiles) * 256;
    const int bcol = (swz / Mtiles) * (WN * 64);

    const int frow = lane & 15;
    const int fk   = (lane >> 4) * 8;
    const int rA   = (lane >> 4) * 4;

    // ---- runtime C/D layout probe (validated rounds 4-6) ----
    half8 pa, pb;
    #pragma unroll
    for (int e = 0; e < 8; ++e) {
        pa[e] = (_Float16)((frow == fk + e) ? 1.0f : 0.0f);
        pb[e] = (_Float16)(float)((fk + e) + 100 * frow);
    }
    float4v pd = {0.f, 0.f, 0.f, 0.f};
    pd = __builtin_amdgcn_mfma_f32_16x16x32_f16(pa, pb, pd, 0, 0, 0);
    const bool m1_ok = (pd[0] == (float)(rA + 0 + 100 * frow)) &&
                       (pd[1] == (float)(rA + 1 + 100 * frow));
    const bool swap_cd = (__ballot(m1_ok) != ~0ull);

    // swizzled LDS read column offsets (bytes within a 128B row)
    const int lrow = frow << 7;
    const int xr   = (lane & 7) << 4;
    const int g16  = ((lane >> 4) & 3) << 4;
    const int c0   = g16 ^ xr;          // ks=0
    const int c1   = (64 + g16) ^ xr;   // ks=1

    const _Float16* Ag = A + (size_t)brow * K;
    const _Float16* Bg = B + (size_t)bcol * K;

    auto stage_tile = [&](int kt, int buf) {
        _Float16* base = lds + buf * BUFH;
        const _Float16* ga = Ag + (size_t)kt * 64;
        stage_half<THREADS>(ga,                  K, base,         tid);
        stage_half<THREADS>(ga + (size_t)128*K,  K, base + 8192,  tid);
        const _Float16* gb = Bg + (size_t)kt * 64;
        stage_half<THREADS>(gb,                  K, base + 16384, tid);
        if constexpr (WN == 4)
            stage_half<THREADS>(gb + (size_t)128*K, K, base + 24576, tid);
    };

    const int NT = K >> 6;

    stage_tile(0, 0);
    VMC(0);
    BAR();

    float4v acc[8][4];
    #pragma unroll
    for (int m = 0; m < 8; ++m)
        #pragma unroll
        for (int n = 0; n < 4; ++n)
            acc[m][n] = (float4v){0.f, 0.f, 0.f, 0.f};

    int cur = 0;
    for (int t = 0; t < NT; ++t) {
        const char* bufc = (const char*)(lds + cur * BUFH);
        const char* Ablk = bufc + wm * 16384;
        const char* Bblk = bufc + 32768 + wn * 8192;
        const bool  pre  = (t + 1 < NT);

        // phase A reads: all A fragments + B fn0-1
        half8 a[8][2], b0[2][2], b1[2][2];
        #pragma unroll
        for (int fm = 0; fm < 8; ++fm) {
            a[fm][0] = *(const half8*)(Ablk + fm * 2048 + lrow + c0);
            a[fm][1] = *(const half8*)(Ablk + fm * 2048 + lrow + c1);
        }
        #pragma unroll
        for (int fn = 0; fn < 2; ++fn) {
            b0[fn][0] = *(const half8*)(Bblk + fn * 2048 + lrow + c0);
            b0[fn][1] = *(const half8*)(Bblk + fn * 2048 + lrow + c1);
        }
        if (pre) stage_tile(t + 1, cur ^ 1);
        // phase B reads issued early (counted wait lets them fly under cluster 1)
        #pragma unroll
        for (int fn = 0; fn < 2; ++fn) {
            b1[fn][0] = *(const half8*)(Bblk + (2 + fn) * 2048 + lrow + c0);
            b1[fn][1] = *(const half8*)(Bblk + (2 + fn) * 2048 + lrow + c1);
        }

        LGKM(4);   // A + b0 landed; b1 (4 reads) may fly
        __builtin_amdgcn_s_setprio(1);
        #pragma unroll
        for (int ks = 0; ks < 2; ++ks)
            #pragma unroll
            for (int fm = 0; fm < 8; ++fm)
                #pragma unroll
                for (int fn = 0; fn < 2; ++fn)
                    acc[fm][fn] = __builtin_amdgcn_mfma_f32_16x16x32_f16(
                        a[fm][ks], b0[fn][ks], acc[fm][fn], 0, 0, 0);
        __builtin_amdgcn_s_setprio(0);

        LGKM(0);
        __builtin_amdgcn_s_setprio(1);
        #pragma unroll
        for (int ks = 0; ks < 2; ++ks)
            #pragma unroll
            for (int fm = 0; fm < 8; ++fm)
                #pragma unroll
                for (int fn = 0; fn < 2; ++fn)
                    acc[fm][2 + fn] = __builtin_amdgcn_mfma_f32_16x16x32_f16(
                        a[fm][ks], b1[fn][ks], acc[fm][2 + fn], 0, 0, 0);
        __builtin_amdgcn_s_setprio(0);

        if (pre) {
            VMC(0);    // my t+1 staging landed (issued ~full tile earlier)
            BAR();     // everyone's landed; all reads of cur done
            cur ^= 1;
        }
    }

    // ---- epilogue ----
    #pragma unroll
    for (int fm = 0; fm < 8; ++fm) {
        #pragma unroll
        for (int fn = 0; fn < 4; ++fn) {
            #pragma unroll
            for (int g = 0; g < 4; ++g) {
                const int fr = swap_cd ? frow : (rA + g);
                const int fc = swap_cd ? (rA + g) : frow;
                const int gr = brow + wm * 128 + fm * 16 + fr;
                const int gc = bcol + wn * 64 + fn * 16 + fc;
                const float v = acc[fm][fn][g] + bias[gc];
                if constexpr (EPI == 0) {
                    ((_Float16*)Cout)[(size_t)gr * Nd + gc] = (_Float16)gelu_exact(v);
                } else {
                    ((float*)Cout)[(size_t)gr * Nd + gc] = (float)(_Float16)v;
                }
            }
        }
    }
}

extern "C" void kernel_launch(void* const* d_in, const int* in_sizes, int n_in,
                              void* d_out, int out_size, void* d_ws, size_t ws_size,
                              hipStream_t stream) {
    const float* x  = (const float*)d_in[0];
    const float* W0 = (const float*)d_in[1];
    const float* b0 = (const float*)d_in[2];
    const float* W1 = (const float*)d_in[3];
    const float* b1 = (const float*)d_in[4];

    const int N = in_sizes[2];           // 8192
    const int H = in_sizes[4];           // 2048
    const int M = in_sizes[0] / H;       // 4096

    const size_t szX  = (size_t)M * H;
    const size_t szW0 = (size_t)N * H;
    const size_t szW1 = (size_t)H * N;

    _Float16* Xh  = (_Float16*)d_ws;
    _Float16* W0h = Xh + szX;
    _Float16* W1h = W0h + szW0;
    _Float16* D   = W1h + szW1;

    cast_f32_f16_kernel<<<2048, 256, 0, stream>>>(x,  Xh,  (int)(szX  / 4));
    cast_f32_f16_kernel<<<2048, 256, 0, stream>>>(W0, W0h, (int)(szW0 / 4));
    cast_f32_f16_kernel<<<2048, 256, 0, stream>>>(W1, W1h, (int)(szW1 / 4));

    const int lds0 = 2 * (16384 + 4 * 4096) * 2;   // 131072 B
    const int lds1 = 2 * (16384 + 2 * 4096) * 2;   //  98304 B
    (void)hipFuncSetAttribute(reinterpret_cast<const void*>(gemm_pw<4, 512, 0>),
                              hipFuncAttributeMaxDynamicSharedMemorySize, lds0);
    (void)hipFuncSetAttribute(reinterpret_cast<const void*>(gemm_pw<2, 256, 1>),
                              hipFuncAttributeMaxDynamicSharedMemorySize, lds1);

    // GEMM0: D = gelu(Xh @ W0h^T + b0)  tiles 256x256 -> 16x32 = 512 wgs
    gemm_pw<4, 512, 0><<<dim3((M / 256) * (N / 256)), dim3(512), lds0, stream>>>(
        Xh, W0h, b0, D, M, N, H, M / 256, N / 256);
    // GEMM1: out = D @ W1h^T + b1       tiles 256x128 -> 16x16 = 256 wgs
    gemm_pw<2, 256, 1><<<dim3((M / 256) * (H / 128)), dim3(256), lds1, stream>>>(
        D, W1h, b1, d_out, M, H, N, M / 256, H / 128);
}